// Round 8
// baseline (341.252 us; speedup 1.0000x reference)
//
#include <hip/hip_runtime.h>

#define N_TOK    8192
#define D_DIM    1024
#define F_DIM    1024
#define NESH     9          // 8 routed experts + shared as expert 8
#define MAX_RTD  18432
#define MAX_ROWS 26624      // MAX_RTD + shared (8192)
#define BM 256
#define BK 64
#define NK 16               // K-tiles (K=1024 / 64)

// meta layout (ints)
#define MO 16   // off_e[9]
#define MT 25   // total rows

typedef float  f4    __attribute__((ext_vector_type(4)));
typedef float  f32x4 __attribute__((ext_vector_type(4)));
typedef short  s16x8 __attribute__((ext_vector_type(8)));
typedef unsigned short u16x8 __attribute__((ext_vector_type(8)));
typedef unsigned short u16x4 __attribute__((ext_vector_type(4)));

static __device__ __forceinline__ unsigned short f2bf(float f) {
    union { float f; unsigned u; } v; v.f = f;
    unsigned r = v.u + 0x7FFFu + ((v.u >> 16) & 1u);
    return (unsigned short)(r >> 16);
}
static __device__ __forceinline__ float bf2f(unsigned short u) {
    union { unsigned u; float f; } v; v.u = ((unsigned)u) << 16; return v.f;
}

#define GLDS(gp, lp) __builtin_amdgcn_global_load_lds( \
    (const __attribute__((address_space(1))) void*)(gp), \
    (__attribute__((address_space(3))) void*)(lp), 16, 0, 0)

// ------------------------------------------- transpose+convert 27 matrices
__global__ __launch_bounds__(256) void k_transpose(
    const float* __restrict__ wg, const float* __restrict__ wu,
    const float* __restrict__ wd, const float* __restrict__ sg,
    const float* __restrict__ su, const float* __restrict__ sd,
    unsigned short* __restrict__ wgt, unsigned short* __restrict__ wut,
    unsigned short* __restrict__ wdt)
{
    int bx = blockIdx.x;
    int m = bx >> 8;                // 0..26
    int tile = bx & 255;
    int ty = tile >> 4, tx = tile & 15;
    int set = m / 9, e = m % 9;
    const float* src; unsigned short* dst;
    if (set == 0)      { src = (e < 8) ? wg + (size_t)e*1048576 : sg; dst = wgt + (size_t)e*1048576; }
    else if (set == 1) { src = (e < 8) ? wu + (size_t)e*1048576 : su; dst = wut + (size_t)e*1048576; }
    else               { src = (e < 8) ? wd + (size_t)e*1048576 : sd; dst = wdt + (size_t)e*1048576; }

    __shared__ unsigned short ts[64 * 67];
    int t = threadIdx.x;
    int rT0 = ty * 64, cT0 = tx * 64;
    #pragma unroll
    for (int i = 0; i < 4; i++) {
        int idx = t + i * 256;
        int a  = idx >> 4;
        int b4 = (idx & 15) * 4;
        f4 v = *(const f4*)(src + (size_t)(cT0 + a) * 1024 + rT0 + b4);
        ts[a * 67 + b4 + 0] = f2bf(v[0]);
        ts[a * 67 + b4 + 1] = f2bf(v[1]);
        ts[a * 67 + b4 + 2] = f2bf(v[2]);
        ts[a * 67 + b4 + 3] = f2bf(v[3]);
    }
    __syncthreads();
    #pragma unroll
    for (int i = 0; i < 2; i++) {
        int slot = t + i * 256;
        int r  = slot >> 3;
        int c8 = (slot & 7) * 8;
        u16x8 o;
        #pragma unroll
        for (int k = 0; k < 8; k++) o[k] = ts[(c8 + k) * 67 + r];
        *(u16x8*)&dst[(size_t)(rT0 + r) * 1024 + cT0 + c8] = o;
    }
}

// ---------------------------------------------- router + x->bf16 convert (fused)
__global__ __launch_bounds__(256) void k_router(
    const float* __restrict__ x, const float* __restrict__ rw,
    unsigned short* __restrict__ xb,
    int* __restrict__ tk_i, float* __restrict__ tk_w)
{
    int wid = threadIdx.x >> 6, lane = threadIdx.x & 63;
    int n = blockIdx.x * 4 + wid;
    const float* xr = x + (size_t)n * D_DIM;
    unsigned short* xbr = xb + (size_t)n * D_DIM;
    float acc[8] = {0,0,0,0,0,0,0,0};
    #pragma unroll
    for (int it = 0; it < 4; it++) {
        int d0 = it * 256 + lane * 4;
        f4 xv = *(const f4*)(xr + d0);
        #pragma unroll
        for (int j = 0; j < 4; j++) {
            f4 r0 = *(const f4*)(rw + (size_t)(d0 + j) * 8);
            f4 r1 = *(const f4*)(rw + (size_t)(d0 + j) * 8 + 4);
            acc[0] += xv[j]*r0[0]; acc[1] += xv[j]*r0[1]; acc[2] += xv[j]*r0[2]; acc[3] += xv[j]*r0[3];
            acc[4] += xv[j]*r1[0]; acc[5] += xv[j]*r1[1]; acc[6] += xv[j]*r1[2]; acc[7] += xv[j]*r1[3];
        }
        u16x4 o; o[0]=f2bf(xv[0]); o[1]=f2bf(xv[1]); o[2]=f2bf(xv[2]); o[3]=f2bf(xv[3]);
        *(u16x4*)&xbr[d0] = o;
    }
    #pragma unroll
    for (int e = 0; e < 8; e++)
        for (int off = 32; off; off >>= 1)
            acc[e] += __shfl_xor(acc[e], off, 64);
    if (lane == 0) {
        float mx = acc[0];
        for (int e = 1; e < 8; e++) mx = fmaxf(mx, acc[e]);
        float p[8], s = 0.f;
        for (int e = 0; e < 8; e++) { p[e] = expf(acc[e] - mx); s += p[e]; }
        int i0 = 0;
        for (int e = 1; e < 8; e++) if (p[e] > p[i0]) i0 = e;
        int i1 = (i0 == 0) ? 1 : 0;
        for (int e = 0; e < 8; e++) if (e != i0 && p[e] > p[i1]) i1 = e;
        float p0 = p[i0] / s, p1 = p[i1] / s;
        float rs = p0 + p1 + 1e-9f;
        tk_i[2*n] = i0;  tk_i[2*n+1] = i1;
        tk_w[2*n] = p0 / rs;  tk_w[2*n+1] = p1 / rs;
    }
}

// --------------- count + offsets + scatter + pad-clear, ONE block, 0 atomics
__global__ __launch_bounds__(1024) void k_count_scatter(
    const int* __restrict__ tk_i, const float* __restrict__ tk_w,
    int* __restrict__ meta,
    int* __restrict__ row_token, int* __restrict__ row_expert,
    int* __restrict__ tok_pos)
{
    __shared__ int cnt[1024 * 9];
    __shared__ int tot[8];
    __shared__ int off[9];
    const int t = threadIdx.x;
    const int lane = t & 63;
    const int wid = t >> 6;

    #pragma unroll
    for (int e = 0; e < 8; e++) cnt[t * 9 + e] = 0;
    __syncthreads();

    #pragma unroll
    for (int j = 0; j < 8; j++) {
        int n = t * 8 + j;
        cnt[t * 9 + tk_i[2 * n]]++;
        cnt[t * 9 + tk_i[2 * n + 1]]++;
    }
    __syncthreads();

    if (wid < 8) {
        const int e = wid;
        int carry = 0;
        for (int c = 0; c < 16; c++) {
            int i = c * 64 + lane;
            int v = cnt[i * 9 + e];
            int s = v;
            #pragma unroll
            for (int d = 1; d < 64; d <<= 1) {
                int u = __shfl_up(s, d, 64);
                if (lane >= d) s += u;
            }
            cnt[i * 9 + e] = s - v + carry;
            carry += __shfl(s, 63, 64);
        }
        if (lane == 0) tot[e] = carry;
    }
    __syncthreads();

    if (t == 0) {
        int acc = 0;
        #pragma unroll
        for (int e = 0; e < 8; e++) {
            off[e] = acc;
            meta[MO + e] = acc;
            acc += ((tot[e] + 255) >> 8) << 8;   // pad to BM=256
        }
        off[8] = acc;
        meta[MO + 8] = acc;
        meta[MT] = acc + N_TOK;
    }
    __syncthreads();

    #pragma unroll
    for (int j = 0; j < 8; j++) {
        int n = t * 8 + j;
        #pragma unroll
        for (int k = 0; k < 2; k++) {
            int e = tk_i[2 * n + k];
            int pos = off[e] + cnt[t * 9 + e];
            cnt[t * 9 + e] = cnt[t * 9 + e] + 1;
            row_token[pos] = n; row_expert[pos] = e;
            tok_pos[2 * n + k] = pos;
        }
        int ps = off[8] + n;
        row_token[ps] = n; row_expert[ps] = 8;
    }
    // clear padding rows
    #pragma unroll
    for (int e = 0; e < 8; e++) {
        int start = off[e] + tot[e], end = off[e + 1];
        for (int i = start + t; i < end; i += 1024) row_token[i] = -1;
    }
}

// ======= GEMM1: gate+up fused; fine-phase schedule: 4 phases/K-tile,
// 16 MFMA/phase, uniform stage quanta (A-halves ph1, B-halves ph2),
// single vmcnt(0) per K-tile draining 2-3-phase-old loads.
// 512 thr, tile 256x128; waves 2M x 4N (per-wave 128x32); LDS 128KB dbuf.
__global__ __launch_bounds__(512, 2) void k_gemm1(
    const unsigned short* __restrict__ xb,
    const unsigned short* __restrict__ wgt,
    const unsigned short* __restrict__ wut,
    const int* __restrict__ row_token,
    const int* __restrict__ row_expert,
    const int* __restrict__ meta,
    unsigned short* __restrict__ h)
{
    const int total = meta[MT];
    const int orig = blockIdx.x;                 // grid 832 = 8*104
    const int bid = (orig & 7) * 104 + (orig >> 3);
    const int rt = bid >> 3, ct = bid & 7;
    const int row0 = rt * BM;
    if (row0 >= total) return;
    const int e = row_expert[row0];

    __shared__ __align__(16) unsigned short sA[2 * 256 * 64];    // 64KB
    __shared__ __align__(16) unsigned short sBg[2 * 128 * 64];   // 32KB
    __shared__ __align__(16) unsigned short sBu[2 * 128 * 64];   // 32KB

    const int t = threadIdx.x;
    const int lane = t & 63;
    const int lr = lane & 15;
    const int kl = lane >> 4;
    const int wid = t >> 6;
    const int wr = wid >> 2, wc = wid & 3;       // per-wave 128M x 32F

    const unsigned short* asrc[4];
    #pragma unroll
    for (int i = 0; i < 4; i++) {
        int slot = t + i * 512;           // 0..2047
        int row = slot >> 3;              // 0..255
        int cg  = (slot & 7) ^ (row & 7);
        int tok = row_token[row0 + row];
        if (tok < 0) tok = 0;
        asrc[i] = xb + (size_t)tok * D_DIM + cg * 8;
    }
    const unsigned short* bsrcg[2];
    const unsigned short* bsrcu[2];
    #pragma unroll
    for (int i = 0; i < 2; i++) {
        int slot = t + i * 512;           // 0..1023
        int row = slot >> 3;              // 0..127
        int cg  = (slot & 7) ^ (row & 7);
        size_t off = ((size_t)e * F_DIM + ct * 128 + row) * D_DIM + cg * 8;
        bsrcg[i] = wgt + off;
        bsrcu[i] = wut + off;
    }

#define ST_A1(bb, k0) do { \
    _Pragma("unroll") \
    for (int i_ = 0; i_ < 4; i_++) \
        GLDS(asrc[i_] + (k0), &sA[(bb) * 16384 + (t + i_ * 512) * 8]); \
    } while (0)
#define ST_B1(bb, k0) do { \
    _Pragma("unroll") \
    for (int i_ = 0; i_ < 2; i_++) { \
        GLDS(bsrcg[i_] + (k0), &sBg[(bb) * 8192 + (t + i_ * 512) * 8]); \
        GLDS(bsrcu[i_] + (k0), &sBu[(bb) * 8192 + (t + i_ * 512) * 8]); \
    } } while (0)

    f32x4 accg[8][2] = {}, accu[8][2] = {};
    s16x8 a_[4], g_[2], u_[2];

#define G1_PHASE(bb, mh, kk, RB, STG, VM) do { \
    const unsigned short* pA = &sA[(bb) * 16384]; \
    const unsigned short* pG = &sBg[(bb) * 8192]; \
    const unsigned short* pU = &sBu[(bb) * 8192]; \
    _Pragma("unroll") \
    for (int mi = 0; mi < 4; mi++) { \
        int row = wr * 128 + (mh) * 64 + mi * 16 + lr; \
        a_[mi] = *(const s16x8*)&pA[(row * 64 + (kk) * 32 + kl * 8) ^ ((row & 7) << 3)]; } \
    if (RB) { \
        _Pragma("unroll") \
        for (int ni = 0; ni < 2; ni++) { \
            int row = wc * 32 + ni * 16 + lr; \
            int ix = (row * 64 + (kk) * 32 + kl * 8) ^ ((row & 7) << 3); \
            g_[ni] = *(const s16x8*)&pG[ix]; \
            u_[ni] = *(const s16x8*)&pU[ix]; } } \
    STG; \
    VM; \
    __builtin_amdgcn_s_barrier(); \
    __builtin_amdgcn_s_setprio(1); \
    _Pragma("unroll") \
    for (int mi = 0; mi < 4; mi++) \
        _Pragma("unroll") \
        for (int ni = 0; ni < 2; ni++) { \
            accg[(mh)*4+mi][ni] = __builtin_amdgcn_mfma_f32_16x16x32_bf16(a_[mi], g_[ni], accg[(mh)*4+mi][ni], 0, 0, 0); \
            accu[(mh)*4+mi][ni] = __builtin_amdgcn_mfma_f32_16x16x32_bf16(a_[mi], u_[ni], accu[(mh)*4+mi][ni], 0, 0, 0); } \
    __builtin_amdgcn_s_setprio(0); \
    __builtin_amdgcn_s_barrier(); \
} while (0)

    // prologue: K-tile 0 fully staged
    ST_A1(0, 0);
    ST_B1(0, 0);
    asm volatile("s_waitcnt vmcnt(0)" ::: "memory");
    __builtin_amdgcn_s_barrier();

    for (int u = 0; u < NK; u++) {
        const int b = u & 1, nb = b ^ 1;
        const int k1 = (u + 1) * BK;
        G1_PHASE(b, 0, 0, 1, if (u < NK-1) ST_A1(nb, k1), );
        G1_PHASE(b, 1, 0, 0, if (u < NK-1) ST_B1(nb, k1), );
        G1_PHASE(b, 0, 1, 1, , );
        G1_PHASE(b, 1, 1, 0, ,
                 if (u < NK-1) { asm volatile("s_waitcnt vmcnt(0)" ::: "memory"); });
    }

    #pragma unroll
    for (int mf = 0; mf < 8; mf++)
        #pragma unroll
        for (int r = 0; r < 4; r++) {
            int grow = row0 + wr * 128 + mf * 16 + (lane >> 4) * 4 + r;
            unsigned short* hrow = h + (size_t)grow * F_DIM + ct * 128 + wc * 32 + lr;
            #pragma unroll
            for (int ni = 0; ni < 2; ni++) {
                float g = accg[mf][ni][r], uu = accu[mf][ni][r];
                float sv = g / (1.f + __expf(-g));
                hrow[ni * 16] = f2bf(sv * uu);
            }
        }
#undef ST_A1
#undef ST_B1
#undef G1_PHASE
}

// ======= GEMM2: down-proj; same fine-phase schedule; tile 256x256 (m201 geom)
// 512 thr, waves 2M x 4N (per-wave 128x64); LDS 128KB dbuf. NO atomics.
__global__ __launch_bounds__(512, 2) void k_gemm2(
    const unsigned short* __restrict__ h,
    const unsigned short* __restrict__ wdt,
    const int* __restrict__ row_expert,
    const int* __restrict__ meta,
    unsigned short* __restrict__ eo,
    float* __restrict__ out)
{
    const int total = meta[MT];
    const int off8 = meta[MO + 8];
    const int orig = blockIdx.x;                 // grid 416 = 8*52
    const int bid = (orig & 7) * 52 + (orig >> 3);
    const int rt = bid >> 2, ct = bid & 3;
    const int row0 = rt * BM;
    if (row0 >= total) return;
    const int e = row_expert[row0];

    __shared__ __align__(16) unsigned short sA[2 * 256 * 64];    // 64KB
    __shared__ __align__(16) unsigned short sB[2 * 256 * 64];    // 64KB

    const int t = threadIdx.x;
    const int lane = t & 63;
    const int lr = lane & 15;
    const int kl = lane >> 4;
    const int wid = t >> 6;
    const int wr = wid >> 2, wc = wid & 3;       // per-wave 128M x 64F

    const unsigned short* asrc[4];
    const unsigned short* bsrc[4];
    #pragma unroll
    for (int i = 0; i < 4; i++) {
        int slot = t + i * 512;
        int row = slot >> 3;
        int cg  = (slot & 7) ^ (row & 7);
        asrc[i] = h + (size_t)(row0 + row) * F_DIM + cg * 8;
        bsrc[i] = wdt + ((size_t)e * D_DIM + ct * 256 + row) * F_DIM + cg * 8;
    }

#define ST_A2(bb, k0) do { \
    _Pragma("unroll") \
    for (int i_ = 0; i_ < 4; i_++) \
        GLDS(asrc[i_] + (k0), &sA[(bb) * 16384 + (t + i_ * 512) * 8]); \
    } while (0)
#define ST_B2(bb, k0) do { \
    _Pragma("unroll") \
    for (int i_ = 0; i_ < 4; i_++) \
        GLDS(bsrc[i_] + (k0), &sB[(bb) * 16384 + (t + i_ * 512) * 8]); \
    } while (0)

    f32x4 acc[8][4] = {};
    s16x8 a_[4], b_[4];

#define G2_PHASE(bb, mh, kk, RB, STG, VM) do { \
    const unsigned short* pA = &sA[(bb) * 16384]; \
    const unsigned short* pB = &sB[(bb) * 16384]; \
    _Pragma("unroll") \
    for (int mi = 0; mi < 4; mi++) { \
        int row = wr * 128 + (mh) * 64 + mi * 16 + lr; \
        a_[mi] = *(const s16x8*)&pA[(row * 64 + (kk) * 32 + kl * 8) ^ ((row & 7) << 3)]; } \
    if (RB) { \
        _Pragma("unroll") \
        for (int ni = 0; ni < 4; ni++) { \
            int row = wc * 64 + ni * 16 + lr; \
            b_[ni] = *(const s16x8*)&pB[(row * 64 + (kk) * 32 + kl * 8) ^ ((row & 7) << 3)]; } } \
    STG; \
    VM; \
    __builtin_amdgcn_s_barrier(); \
    __builtin_amdgcn_s_setprio(1); \
    _Pragma("unroll") \
    for (int mi = 0; mi < 4; mi++) \
        _Pragma("unroll") \
        for (int ni = 0; ni < 4; ni++) \
            acc[(mh)*4+mi][ni] = __builtin_amdgcn_mfma_f32_16x16x32_bf16(a_[mi], b_[ni], acc[(mh)*4+mi][ni], 0, 0, 0); \
    __builtin_amdgcn_s_setprio(0); \
    __builtin_amdgcn_s_barrier(); \
} while (0)

    ST_A2(0, 0);
    ST_B2(0, 0);
    asm volatile("s_waitcnt vmcnt(0)" ::: "memory");
    __builtin_amdgcn_s_barrier();

    for (int u = 0; u < NK; u++) {
        const int b = u & 1, nb = b ^ 1;
        const int k1 = (u + 1) * BK;
        G2_PHASE(b, 0, 0, 1, if (u < NK-1) ST_A2(nb, k1), );
        G2_PHASE(b, 1, 0, 0, if (u < NK-1) ST_B2(nb, k1), );
        G2_PHASE(b, 0, 1, 1, , );
        G2_PHASE(b, 1, 1, 0, ,
                 if (u < NK-1) { asm volatile("s_waitcnt vmcnt(0)" ::: "memory"); });
    }

    if (e < 8) {
        #pragma unroll
        for (int mf = 0; mf < 8; mf++)
            #pragma unroll
            for (int r = 0; r < 4; r++) {
                int grow = row0 + wr * 128 + mf * 16 + (lane >> 4) * 4 + r;
                unsigned short* erow = eo + (size_t)grow * D_DIM + ct * 256 + wc * 64 + lr;
                #pragma unroll
                for (int ni = 0; ni < 4; ni++)
                    erow[ni * 16] = f2bf(acc[mf][ni][r]);
            }
    } else {
        #pragma unroll
        for (int mf = 0; mf < 8; mf++)
            #pragma unroll
            for (int r = 0; r < 4; r++) {
                int grow = row0 + wr * 128 + mf * 16 + (lane >> 4) * 4 + r;
                int tok = grow - off8;
                float* orow = out + (size_t)tok * D_DIM + ct * 256 + wc * 64 + lr;
                #pragma unroll
                for (int ni = 0; ni < 4; ni++)
                    orow[ni * 16] = acc[mf][ni][r];
            }
    }
#undef ST_A2
#undef ST_B2
#undef G2_PHASE
}

// ---------------------------------------- combine: out += w0*eo[p0] + w1*eo[p1]
__global__ __launch_bounds__(256) void k_combine(
    const unsigned short* __restrict__ eo,
    const int* __restrict__ tok_pos, const float* __restrict__ tk_w,
    float* __restrict__ out)
{
    const int t = threadIdx.x;
    const int n = blockIdx.x * 2 + (t >> 7);
    const int c0 = (t & 127) * 8;
    const int p0 = tok_pos[2 * n], p1 = tok_pos[2 * n + 1];
    const float w0 = tk_w[2 * n], w1 = tk_w[2 * n + 1];
    u16x8 a = *(const u16x8*)&eo[(size_t)p0 * D_DIM + c0];
    u16x8 b = *(const u16x8*)&eo[(size_t)p1 * D_DIM + c0];
    float* orow = out + (size_t)n * D_DIM + c0;
    f4 o0 = *(f4*)orow, o1 = *(f4*)(orow + 4);
    #pragma unroll
    for (int j = 0; j < 4; j++) {
        o0[j] += w0 * bf2f(a[j])     + w1 * bf2f(b[j]);
        o1[j] += w0 * bf2f(a[4 + j]) + w1 * bf2f(b[4 + j]);
    }
    *(f4*)orow = o0;
    *(f4*)(orow + 4) = o1;
}

// ---------------------------------------------------------------- launch
extern "C" void kernel_launch(void* const* d_in, const int* in_sizes, int n_in,
                              void* d_out, int out_size, void* d_ws, size_t ws_size,
                              hipStream_t stream)
{
    const float* x  = (const float*)d_in[0];
    const float* rw = (const float*)d_in[1];
    const float* sg = (const float*)d_in[2];
    const float* su = (const float*)d_in[3];
    const float* sd = (const float*)d_in[4];
    const float* wg = (const float*)d_in[5];
    const float* wu = (const float*)d_in[6];
    const float* wd = (const float*)d_in[7];
    float* out = (float*)d_out;

    char* p = (char*)d_ws;
    unsigned short* xb  = (unsigned short*)p; p += (size_t)N_TOK * D_DIM * 2;
    unsigned short* wgt = (unsigned short*)p; p += (size_t)NESH * D_DIM * F_DIM * 2;
    unsigned short* wut = (unsigned short*)p; p += (size_t)NESH * D_DIM * F_DIM * 2;
    unsigned short* wdt = (unsigned short*)p; p += (size_t)NESH * D_DIM * F_DIM * 2;
    unsigned short* h   = (unsigned short*)p; p += (size_t)MAX_ROWS * F_DIM * 2;
    int*   row_token  = (int*)p;   p += (size_t)MAX_ROWS * 4;
    int*   row_expert = (int*)p;   p += (size_t)MAX_ROWS * 4;
    int*   tok_pos = (int*)p;      p += (size_t)N_TOK * 2 * 4;
    int*   tk_i = (int*)p;         p += (size_t)N_TOK * 2 * 4;
    float* tk_w = (float*)p;       p += (size_t)N_TOK * 2 * 4;
    int*   meta = (int*)p;         p += 1024;
    if ((size_t)(p - (char*)d_ws) > ws_size) return;

    // eo (routed down-proj output, bf16, MAX_RTD x D) aliases wgt+wut (dead
    // after k_gemm1, rewritten by k_transpose each call).
    unsigned short* eo = wgt;

    k_router<<<N_TOK / 4, 256, 0, stream>>>(x, rw, xb, tk_i, tk_w);
    k_transpose<<<27 * 256, 256, 0, stream>>>(wg, wu, wd, sg, su, sd, wgt, wut, wdt);
    k_count_scatter<<<1, 1024, 0, stream>>>(tk_i, tk_w, meta, row_token, row_expert, tok_pos);
    k_gemm1<<<(MAX_ROWS / BM) * 8, 512, 0, stream>>>(xb, wgt, wut, row_token, row_expert, meta, h);
    k_gemm2<<<(MAX_ROWS / BM) * 4, 512, 0, stream>>>(h, wdt, row_expert, meta, eo, out);
    k_combine<<<N_TOK / 2, 256, 0, stream>>>(eo, tok_pos, tk_w, out);
}

// Round 9
// 317.318 us; speedup vs baseline: 1.0754x; 1.0754x over previous
//
#include <hip/hip_runtime.h>

#define N_TOK    8192
#define D_DIM    1024
#define F_DIM    1024
#define NESH     9          // 8 routed experts + shared as expert 8
#define MAX_RTD  17408      // 16384 + 8*128
#define MAX_ROWS 26624      // >= MAX_RTD + shared (8192)
#define BT 128              // tile dim (M and N)
#define BK 32
#define NK 32               // K-tiles (K=1024 / 32)

// meta layout (ints)
#define MO 16   // off_e[9]
#define MT 25   // total rows

typedef float  f4    __attribute__((ext_vector_type(4)));
typedef float  f32x4 __attribute__((ext_vector_type(4)));
typedef short  s16x8 __attribute__((ext_vector_type(8)));
typedef unsigned short u16x8 __attribute__((ext_vector_type(8)));
typedef unsigned short u16x4 __attribute__((ext_vector_type(4)));

static __device__ __forceinline__ unsigned short f2bf(float f) {
    union { float f; unsigned u; } v; v.f = f;
    unsigned r = v.u + 0x7FFFu + ((v.u >> 16) & 1u);
    return (unsigned short)(r >> 16);
}
static __device__ __forceinline__ float bf2f(unsigned short u) {
    union { unsigned u; float f; } v; v.u = ((unsigned)u) << 16; return v.f;
}

#define GLDS(gp, lp) __builtin_amdgcn_global_load_lds( \
    (const __attribute__((address_space(1))) void*)(gp), \
    (__attribute__((address_space(3))) void*)(lp), 16, 0, 0)

// ------------------------------------------- transpose+convert 27 matrices
__global__ __launch_bounds__(256) void k_transpose(
    const float* __restrict__ wg, const float* __restrict__ wu,
    const float* __restrict__ wd, const float* __restrict__ sg,
    const float* __restrict__ su, const float* __restrict__ sd,
    unsigned short* __restrict__ wgt, unsigned short* __restrict__ wut,
    unsigned short* __restrict__ wdt)
{
    int bx = blockIdx.x;
    int m = bx >> 8;                // 0..26
    int tile = bx & 255;
    int ty = tile >> 4, tx = tile & 15;
    int set = m / 9, e = m % 9;
    const float* src; unsigned short* dst;
    if (set == 0)      { src = (e < 8) ? wg + (size_t)e*1048576 : sg; dst = wgt + (size_t)e*1048576; }
    else if (set == 1) { src = (e < 8) ? wu + (size_t)e*1048576 : su; dst = wut + (size_t)e*1048576; }
    else               { src = (e < 8) ? wd + (size_t)e*1048576 : sd; dst = wdt + (size_t)e*1048576; }

    __shared__ unsigned short ts[64 * 67];
    int t = threadIdx.x;
    int rT0 = ty * 64, cT0 = tx * 64;
    #pragma unroll
    for (int i = 0; i < 4; i++) {
        int idx = t + i * 256;
        int a  = idx >> 4;
        int b4 = (idx & 15) * 4;
        f4 v = *(const f4*)(src + (size_t)(cT0 + a) * 1024 + rT0 + b4);
        ts[a * 67 + b4 + 0] = f2bf(v[0]);
        ts[a * 67 + b4 + 1] = f2bf(v[1]);
        ts[a * 67 + b4 + 2] = f2bf(v[2]);
        ts[a * 67 + b4 + 3] = f2bf(v[3]);
    }
    __syncthreads();
    #pragma unroll
    for (int i = 0; i < 2; i++) {
        int slot = t + i * 256;
        int r  = slot >> 3;
        int c8 = (slot & 7) * 8;
        u16x8 o;
        #pragma unroll
        for (int k = 0; k < 8; k++) o[k] = ts[(c8 + k) * 67 + r];
        *(u16x8*)&dst[(size_t)(rT0 + r) * 1024 + cT0 + c8] = o;
    }
}

// ---------------------------------------------- router + x->bf16 convert (fused)
__global__ __launch_bounds__(256) void k_router(
    const float* __restrict__ x, const float* __restrict__ rw,
    unsigned short* __restrict__ xb,
    int* __restrict__ tk_i, float* __restrict__ tk_w)
{
    int wid = threadIdx.x >> 6, lane = threadIdx.x & 63;
    int n = blockIdx.x * 4 + wid;
    const float* xr = x + (size_t)n * D_DIM;
    unsigned short* xbr = xb + (size_t)n * D_DIM;
    float acc[8] = {0,0,0,0,0,0,0,0};
    #pragma unroll
    for (int it = 0; it < 4; it++) {
        int d0 = it * 256 + lane * 4;
        f4 xv = *(const f4*)(xr + d0);
        #pragma unroll
        for (int j = 0; j < 4; j++) {
            f4 r0 = *(const f4*)(rw + (size_t)(d0 + j) * 8);
            f4 r1 = *(const f4*)(rw + (size_t)(d0 + j) * 8 + 4);
            acc[0] += xv[j]*r0[0]; acc[1] += xv[j]*r0[1]; acc[2] += xv[j]*r0[2]; acc[3] += xv[j]*r0[3];
            acc[4] += xv[j]*r1[0]; acc[5] += xv[j]*r1[1]; acc[6] += xv[j]*r1[2]; acc[7] += xv[j]*r1[3];
        }
        u16x4 o; o[0]=f2bf(xv[0]); o[1]=f2bf(xv[1]); o[2]=f2bf(xv[2]); o[3]=f2bf(xv[3]);
        *(u16x4*)&xbr[d0] = o;
    }
    #pragma unroll
    for (int e = 0; e < 8; e++)
        for (int off = 32; off; off >>= 1)
            acc[e] += __shfl_xor(acc[e], off, 64);
    if (lane == 0) {
        float mx = acc[0];
        for (int e = 1; e < 8; e++) mx = fmaxf(mx, acc[e]);
        float p[8], s = 0.f;
        for (int e = 0; e < 8; e++) { p[e] = expf(acc[e] - mx); s += p[e]; }
        int i0 = 0;
        for (int e = 1; e < 8; e++) if (p[e] > p[i0]) i0 = e;
        int i1 = (i0 == 0) ? 1 : 0;
        for (int e = 0; e < 8; e++) if (e != i0 && p[e] > p[i1]) i1 = e;
        float p0 = p[i0] / s, p1 = p[i1] / s;
        float rs = p0 + p1 + 1e-9f;
        tk_i[2*n] = i0;  tk_i[2*n+1] = i1;
        tk_w[2*n] = p0 / rs;  tk_w[2*n+1] = p1 / rs;
    }
}

// --------------- count + offsets + scatter + pad-clear, ONE block, 0 atomics
__global__ __launch_bounds__(1024) void k_count_scatter(
    const int* __restrict__ tk_i, const float* __restrict__ tk_w,
    int* __restrict__ meta,
    int* __restrict__ row_token, int* __restrict__ row_expert,
    int* __restrict__ tok_pos)
{
    __shared__ int cnt[1024 * 9];
    __shared__ int tot[8];
    __shared__ int off[9];
    const int t = threadIdx.x;
    const int lane = t & 63;
    const int wid = t >> 6;

    #pragma unroll
    for (int e = 0; e < 8; e++) cnt[t * 9 + e] = 0;
    __syncthreads();

    #pragma unroll
    for (int j = 0; j < 8; j++) {
        int n = t * 8 + j;
        cnt[t * 9 + tk_i[2 * n]]++;
        cnt[t * 9 + tk_i[2 * n + 1]]++;
    }
    __syncthreads();

    if (wid < 8) {
        const int e = wid;
        int carry = 0;
        for (int c = 0; c < 16; c++) {
            int i = c * 64 + lane;
            int v = cnt[i * 9 + e];
            int s = v;
            #pragma unroll
            for (int d = 1; d < 64; d <<= 1) {
                int u = __shfl_up(s, d, 64);
                if (lane >= d) s += u;
            }
            cnt[i * 9 + e] = s - v + carry;
            carry += __shfl(s, 63, 64);
        }
        if (lane == 0) tot[e] = carry;
    }
    __syncthreads();

    if (t == 0) {
        int acc = 0;
        #pragma unroll
        for (int e = 0; e < 8; e++) {
            off[e] = acc;
            meta[MO + e] = acc;
            acc += ((tot[e] + 127) >> 7) << 7;   // pad to BT=128
        }
        off[8] = acc;
        meta[MO + 8] = acc;
        meta[MT] = acc + N_TOK;
    }
    __syncthreads();

    #pragma unroll
    for (int j = 0; j < 8; j++) {
        int n = t * 8 + j;
        #pragma unroll
        for (int k = 0; k < 2; k++) {
            int e = tk_i[2 * n + k];
            int pos = off[e] + cnt[t * 9 + e];
            cnt[t * 9 + e] = cnt[t * 9 + e] + 1;
            row_token[pos] = n; row_expert[pos] = e;
            tok_pos[2 * n + k] = pos;
        }
        int ps = off[8] + n;
        row_token[ps] = n; row_expert[ps] = 8;
    }
    // clear padding rows
    #pragma unroll
    for (int e = 0; e < 8; e++) {
        int start = off[e] + tot[e], end = off[e + 1];
        for (int i = start + t; i < end; i += 1024) row_token[i] = -1;
    }
}

// BK=32 swizzle: chunk c (16B) at row r maps c ^= (r>>1)&3.
// Read idx (elems): row*32 + ((kl ^ ((row>>1)&3))<<3), kl = lane>>4.

// ======= GEMM1: gate+up fused; R5 coarse 2-phase loop; 128x128 tile, BK=32,
// dbuf; LDS 48KB; <=128 VGPR; 2 blocks/CU (the m97/m114 occupancy regime).
__global__ __launch_bounds__(512, 4) void k_gemm1(
    const unsigned short* __restrict__ xb,
    const unsigned short* __restrict__ wgt,
    const unsigned short* __restrict__ wut,
    const int* __restrict__ row_token,
    const int* __restrict__ row_expert,
    const int* __restrict__ meta,
    unsigned short* __restrict__ h)
{
    const int total = meta[MT];
    const int orig = blockIdx.x;                 // grid 1664 = 8*208
    const int bid = (orig & 7) * 208 + (orig >> 3);
    const int rt = bid >> 3, ct = bid & 7;
    const int row0 = rt * BT;
    if (row0 >= total) return;
    const int e = row_expert[row0];

    __shared__ __align__(16) unsigned short sA[2 * 128 * 32];   // 16KB
    __shared__ __align__(16) unsigned short sBg[2 * 128 * 32];  // 16KB
    __shared__ __align__(16) unsigned short sBu[2 * 128 * 32];  // 16KB

    const int t = threadIdx.x;
    const int lane = t & 63;
    const int lr = lane & 15;
    const int kl = lane >> 4;
    const int wid = t >> 6;
    const int wr = wid >> 2, wc = wid & 3;       // per-wave 64M x 32N

    // staging: 512 slots = 128 rows x 4 chunks, 1 per thread
    const int srow = t >> 2;
    const int scg  = (t & 3) ^ ((srow >> 1) & 3);
    int tok = row_token[row0 + srow];
    if (tok < 0) tok = 0;
    const unsigned short* srcA = xb + (size_t)tok * D_DIM + scg * 8;
    const unsigned short* srcG = wgt + ((size_t)e * F_DIM + ct * BT + srow) * D_DIM + scg * 8;
    const unsigned short* srcU = wut + ((size_t)e * F_DIM + ct * BT + srow) * D_DIM + scg * 8;

    f32x4 accg[4][2] = {}, accu[4][2] = {};

#define ST1(bb, k0) do { \
    GLDS(srcA + (k0), &sA[(bb) * 4096 + t * 8]); \
    GLDS(srcG + (k0), &sBg[(bb) * 4096 + t * 8]); \
    GLDS(srcU + (k0), &sBu[(bb) * 4096 + t * 8]); } while (0)

#define COMPUTE1(bb) do { \
    const unsigned short* pA  = &sA[(bb) * 4096]; \
    const unsigned short* pG  = &sBg[(bb) * 4096]; \
    const unsigned short* pU  = &sBu[(bb) * 4096]; \
    s16x8 a_[4], g_[2], q_[2]; \
    _Pragma("unroll") \
    for (int m_ = 0; m_ < 4; m_++) { \
        int row = wr * 64 + m_ * 16 + lr; \
        a_[m_] = *(const s16x8*)&pA[row * 32 + ((kl ^ ((row >> 1) & 3)) << 3)]; } \
    _Pragma("unroll") \
    for (int n_ = 0; n_ < 2; n_++) { \
        int row = wc * 32 + n_ * 16 + lr; \
        int ix = row * 32 + ((kl ^ ((row >> 1) & 3)) << 3); \
        g_[n_] = *(const s16x8*)&pG[ix]; \
        q_[n_] = *(const s16x8*)&pU[ix]; } \
    _Pragma("unroll") \
    for (int m_ = 0; m_ < 4; m_++) \
        _Pragma("unroll") \
        for (int n_ = 0; n_ < 2; n_++) { \
            accg[m_][n_] = __builtin_amdgcn_mfma_f32_16x16x32_bf16(a_[m_], g_[n_], accg[m_][n_], 0, 0, 0); \
            accu[m_][n_] = __builtin_amdgcn_mfma_f32_16x16x32_bf16(a_[m_], q_[n_], accu[m_][n_], 0, 0, 0); } \
    } while (0)

    ST1(0, 0);
    for (int u = 0; u < NK; u++) {
        if (u < NK - 1) {
            ST1((u + 1) & 1, (u + 1) * BK);
            asm volatile("s_waitcnt vmcnt(3)" ::: "memory");  // drain tile u
        } else {
            asm volatile("s_waitcnt vmcnt(0)" ::: "memory");
        }
        __builtin_amdgcn_s_barrier();
        __builtin_amdgcn_s_setprio(1);
        COMPUTE1(u & 1);
        __builtin_amdgcn_s_setprio(0);
        asm volatile("" ::: "memory");
        __builtin_amdgcn_s_barrier();
    }

    #pragma unroll
    for (int m = 0; m < 4; m++)
        #pragma unroll
        for (int r = 0; r < 4; r++) {
            int grow = row0 + wr * 64 + m * 16 + (lane >> 4) * 4 + r;
            unsigned short* hrow = h + (size_t)grow * F_DIM + ct * BT + wc * 32 + lr;
            #pragma unroll
            for (int n = 0; n < 2; n++) {
                float g = accg[m][n][r], uu = accu[m][n][r];
                float sv = g / (1.f + __expf(-g));
                hrow[n * 16] = f2bf(sv * uu);
            }
        }
#undef ST1
#undef COMPUTE1
}

// ======= GEMM2: down-proj; same structure; 128x128 tile, BK=32, LDS 32KB.
__global__ __launch_bounds__(512, 4) void k_gemm2(
    const unsigned short* __restrict__ h,
    const unsigned short* __restrict__ wdt,
    const int* __restrict__ row_expert,
    const int* __restrict__ meta,
    unsigned short* __restrict__ eo,
    float* __restrict__ out)
{
    const int total = meta[MT];
    const int off8 = meta[MO + 8];
    const int orig = blockIdx.x;                 // grid 1664 = 8*208
    const int bid = (orig & 7) * 208 + (orig >> 3);
    const int rt = bid >> 3, ct = bid & 7;
    const int row0 = rt * BT;
    if (row0 >= total) return;
    const int e = row_expert[row0];

    __shared__ __align__(16) unsigned short sA[2 * 128 * 32];   // 16KB
    __shared__ __align__(16) unsigned short sB[2 * 128 * 32];   // 16KB

    const int t = threadIdx.x;
    const int lane = t & 63;
    const int lr = lane & 15;
    const int kl = lane >> 4;
    const int wid = t >> 6;
    const int wr = wid >> 2, wc = wid & 3;       // per-wave 64M x 32N

    const int srow = t >> 2;
    const int scg  = (t & 3) ^ ((srow >> 1) & 3);
    const unsigned short* srcA = h + (size_t)(row0 + srow) * F_DIM + scg * 8;
    const unsigned short* srcB = wdt + ((size_t)e * D_DIM + ct * BT + srow) * F_DIM + scg * 8;

    f32x4 acc[4][2] = {};

#define ST2(bb, k0) do { \
    GLDS(srcA + (k0), &sA[(bb) * 4096 + t * 8]); \
    GLDS(srcB + (k0), &sB[(bb) * 4096 + t * 8]); } while (0)

#define COMPUTE2(bb) do { \
    const unsigned short* pA = &sA[(bb) * 4096]; \
    const unsigned short* pB = &sB[(bb) * 4096]; \
    s16x8 a_[4], b_[2]; \
    _Pragma("unroll") \
    for (int m_ = 0; m_ < 4; m_++) { \
        int row = wr * 64 + m_ * 16 + lr; \
        a_[m_] = *(const s16x8*)&pA[row * 32 + ((kl ^ ((row >> 1) & 3)) << 3)]; } \
    _Pragma("unroll") \
    for (int n_ = 0; n_ < 2; n_++) { \
        int row = wc * 32 + n_ * 16 + lr; \
        b_[n_] = *(const s16x8*)&pB[row * 32 + ((kl ^ ((row >> 1) & 3)) << 3)]; } \
    _Pragma("unroll") \
    for (int m_ = 0; m_ < 4; m_++) \
        _Pragma("unroll") \
        for (int n_ = 0; n_ < 2; n_++) \
            acc[m_][n_] = __builtin_amdgcn_mfma_f32_16x16x32_bf16(a_[m_], b_[n_], acc[m_][n_], 0, 0, 0); \
    } while (0)

    ST2(0, 0);
    for (int u = 0; u < NK; u++) {
        if (u < NK - 1) {
            ST2((u + 1) & 1, (u + 1) * BK);
            asm volatile("s_waitcnt vmcnt(2)" ::: "memory");
        } else {
            asm volatile("s_waitcnt vmcnt(0)" ::: "memory");
        }
        __builtin_amdgcn_s_barrier();
        __builtin_amdgcn_s_setprio(1);
        COMPUTE2(u & 1);
        __builtin_amdgcn_s_setprio(0);
        asm volatile("" ::: "memory");
        __builtin_amdgcn_s_barrier();
    }

    if (e < 8) {
        #pragma unroll
        for (int m = 0; m < 4; m++)
            #pragma unroll
            for (int r = 0; r < 4; r++) {
                int grow = row0 + wr * 64 + m * 16 + (lane >> 4) * 4 + r;
                unsigned short* erow = eo + (size_t)grow * D_DIM + ct * BT + wc * 32 + lr;
                #pragma unroll
                for (int n = 0; n < 2; n++)
                    erow[n * 16] = f2bf(acc[m][n][r]);
            }
    } else {
        #pragma unroll
        for (int m = 0; m < 4; m++)
            #pragma unroll
            for (int r = 0; r < 4; r++) {
                int grow = row0 + wr * 64 + m * 16 + (lane >> 4) * 4 + r;
                int tok = grow - off8;
                float* orow = out + (size_t)tok * D_DIM + ct * BT + wc * 32 + lr;
                #pragma unroll
                for (int n = 0; n < 2; n++)
                    orow[n * 16] = acc[m][n][r];
            }
    }
#undef ST2
#undef COMPUTE2
}

// ---------------------------------------- combine: out += w0*eo[p0] + w1*eo[p1]
__global__ __launch_bounds__(256) void k_combine(
    const unsigned short* __restrict__ eo,
    const int* __restrict__ tok_pos, const float* __restrict__ tk_w,
    float* __restrict__ out)
{
    const int t = threadIdx.x;
    const int n = blockIdx.x * 2 + (t >> 7);
    const int c0 = (t & 127) * 8;
    const int p0 = tok_pos[2 * n], p1 = tok_pos[2 * n + 1];
    const float w0 = tk_w[2 * n], w1 = tk_w[2 * n + 1];
    u16x8 a = *(const u16x8*)&eo[(size_t)p0 * D_DIM + c0];
    u16x8 b = *(const u16x8*)&eo[(size_t)p1 * D_DIM + c0];
    float* orow = out + (size_t)n * D_DIM + c0;
    f4 o0 = *(f4*)orow, o1 = *(f4*)(orow + 4);
    #pragma unroll
    for (int j = 0; j < 4; j++) {
        o0[j] += w0 * bf2f(a[j])     + w1 * bf2f(b[j]);
        o1[j] += w0 * bf2f(a[4 + j]) + w1 * bf2f(b[4 + j]);
    }
    *(f4*)orow = o0;
    *(f4*)(orow + 4) = o1;
}

// ---------------------------------------------------------------- launch
extern "C" void kernel_launch(void* const* d_in, const int* in_sizes, int n_in,
                              void* d_out, int out_size, void* d_ws, size_t ws_size,
                              hipStream_t stream)
{
    const float* x  = (const float*)d_in[0];
    const float* rw = (const float*)d_in[1];
    const float* sg = (const float*)d_in[2];
    const float* su = (const float*)d_in[3];
    const float* sd = (const float*)d_in[4];
    const float* wg = (const float*)d_in[5];
    const float* wu = (const float*)d_in[6];
    const float* wd = (const float*)d_in[7];
    float* out = (float*)d_out;

    char* p = (char*)d_ws;
    unsigned short* xb  = (unsigned short*)p; p += (size_t)N_TOK * D_DIM * 2;
    unsigned short* wgt = (unsigned short*)p; p += (size_t)NESH * D_DIM * F_DIM * 2;
    unsigned short* wut = (unsigned short*)p; p += (size_t)NESH * D_DIM * F_DIM * 2;
    unsigned short* wdt = (unsigned short*)p; p += (size_t)NESH * D_DIM * F_DIM * 2;
    unsigned short* h   = (unsigned short*)p; p += (size_t)MAX_ROWS * F_DIM * 2;
    int*   row_token  = (int*)p;   p += (size_t)MAX_ROWS * 4;
    int*   row_expert = (int*)p;   p += (size_t)MAX_ROWS * 4;
    int*   tok_pos = (int*)p;      p += (size_t)N_TOK * 2 * 4;
    int*   tk_i = (int*)p;         p += (size_t)N_TOK * 2 * 4;
    float* tk_w = (float*)p;       p += (size_t)N_TOK * 2 * 4;
    int*   meta = (int*)p;         p += 1024;
    if ((size_t)(p - (char*)d_ws) > ws_size) return;

    // eo (routed down-proj output, bf16, MAX_RTD x D) aliases wgt+wut (dead
    // after k_gemm1, rewritten by k_transpose each call).
    unsigned short* eo = wgt;

    k_router<<<N_TOK / 4, 256, 0, stream>>>(x, rw, xb, tk_i, tk_w);
    k_transpose<<<27 * 256, 256, 0, stream>>>(wg, wu, wd, sg, su, sd, wgt, wut, wdt);
    k_count_scatter<<<1, 1024, 0, stream>>>(tk_i, tk_w, meta, row_token, row_expert, tok_pos);
    k_gemm1<<<(MAX_ROWS / BT) * 8, 512, 0, stream>>>(xb, wgt, wut, row_token, row_expert, meta, h);
    k_gemm2<<<(MAX_ROWS / BT) * 8, 512, 0, stream>>>(h, wdt, row_expert, meta, eo, out);
    k_combine<<<N_TOK / 2, 256, 0, stream>>>(eo, tok_pos, tk_w, out);
}